// Round 6
// baseline (97.660 us; speedup 1.0000x reference)
//
#include <hip/hip_runtime.h>

// MVB (minimum-variance beamformer), fp32. Round 6: channel-split fusion.
//
// Round-5 diagnosis: 65536 px / 64 = 1024 waves = 1 wave/SIMD device-wide.
// Zero TLP -> every LDS-gather latency and barrier vmcnt drain fully exposed.
// Fix: split the 128 channels across 2 waves per 64-pixel group (threads
// 0-127: ch 0-63, threads 128-255: ch 64-127 of the same z-row). 2048 waves
// = 2 waves/SIMD; per-thread work halves. Exact lag-window recombination:
//   F[d] = F_lo[d] + F_hi[d] + sum_{i<d} head_hi[i] * win_lo[16-d+i]
// Lo waves export {F,win,head,Sall} (49 floats/px) through the dead LDS
// tile; hi waves combine + Cholesky-solve + write out.
// LDS 64 KB (2 buf x 2 halves x 4 rows x 4 KB) -> 2 blocks/CU;
// __launch_bounds__(256,2) caps VGPR at 256 for 2 waves/SIMD.

namespace {

constexpr int kB  = 2;
constexpr int kC  = 128;
constexpr int kNS = 1024;
constexpr int kNZ = 256;
constexpr int kNX = 128;
constexpr int kZX = kNZ * kNX;        // 32768
constexpr int kHalfC = 64;            // channels per half
constexpr int kRows = 4;              // rf rows per half per step (16 KB)
constexpr int kBufF = 2 * kRows * kNS;  // floats per buffer (both halves)
constexpr int kTPB = 256;

// packed upper-triangular index, l <= k, 16x16 -> 136 entries
__device__ __host__ constexpr int tri(int l, int k) {
  return l * 16 - (l * (l - 1)) / 2 + (k - l);
}

typedef __attribute__((address_space(1))) const void gconst_t;
typedef __attribute__((address_space(3))) void ldsv_t;

__device__ __forceinline__ void g2l16(const float* g, float* l) {
  // 16B per lane, LDS dest = wave-uniform base + lane*16
  __builtin_amdgcn_global_load_lds((gconst_t*)g, (ldsv_t*)l, 16, 0, 0);
}

// Stage step q: lower half rows ch = q*4..q*4+3 (waves 0-1), upper half rows
// ch = 64+q*4.. (waves 2-3). Each wave: 8 issues x 1 KB = 8 KB. Async.
__device__ __forceinline__ void stage_step(const float* __restrict__ rfb,
                                           float* tbuf, int q, int wave,
                                           int lane) {
  const int h = wave >> 1;
  const int woff = (wave & 1) * 2048;          // floats within the 16 KB half
  const float* gsrc = rfb + (size_t)(h * kHalfC + q * kRows) * kNS;
  float* ldst = tbuf + h * (kRows * kNS);
#pragma unroll
  for (int i = 0; i < 8; ++i)
    g2l16(gsrc + woff + i * 256 + lane * 4, ldst + woff + i * 256);
}

__device__ __forceinline__ void load_drx4(const float* __restrict__ drxp,
                                          int cbase, float (&d)[kRows]) {
#pragma unroll
  for (int r = 0; r < kRows; ++r)
    d[r] = drxp[(size_t)(cbase + r) * kZX];    // coalesced across lanes
}

template <int PH, bool HEAD>
__device__ __forceinline__ void compute4(
    const float* rows, const float (&drx)[kRows], float kk, float base,
    float (&F)[16], float (&win)[16], float (&head)[16], float& Sall) {
#pragma unroll
  for (int r = 0; r < kRows; ++r) {
    const int t = PH + r;                      // local channel & 15 (static)
    float pos = fmaf(kk, drx[r], base);
    pos = fminf(fmaxf(pos, 0.0f), 1023.0f);
    int i0 = (int)pos;                         // pos >= 0: trunc == floor
    i0 = min(i0, kNS - 2);                     // pos==1023 -> frac==1.0
    float frac = pos - (float)i0;
    const float* p = rows + r * kNS + i0;
    float v0 = p[0];                           // ds_read2_b32 pair
    float v1 = p[1];
    float v = fmaf(frac, v1 - v0, v0);
    Sall += v;
    F[0] = fmaf(v, v, F[0]);
    if constexpr (HEAD) {
#pragma unroll
      for (int d = 1; d <= t; ++d) F[d] = fmaf(v, win[t - d], F[d]);
      head[t] = v;
    } else {
#pragma unroll
      for (int d = 1; d < 16; ++d) F[d] = fmaf(v, win[(t - d) & 15], F[d]);
    }
    win[t] = v;
  }
}

#define STEP(Q, PH, HEADF, CUR, NXT)                                       \
  do {                                                                     \
    if ((Q) + 1 < 16) {                                                    \
      stage_step(rfb, tile[((Q) + 1) & 1], (Q) + 1, wave, lane);           \
      load_drx4(drxp, ((Q) + 1) * kRows, NXT);                             \
    }                                                                      \
    compute4<PH, HEADF>(tile[(Q) & 1] + half * (kRows * kNS), CUR, kk,     \
                        base, F, win, head, Sall);                         \
    __syncthreads();                                                       \
  } while (0)

// ---------------- Fused kernel: split window + combine + solve -------------
__global__ __launch_bounds__(kTPB, 2) void mvb_fused_kernel(
    const float* __restrict__ rf, const float* __restrict__ t0,
    const float* __restrict__ d_tx, const float* __restrict__ d_rx,
    const float* __restrict__ fs_p, const float* __restrict__ c0_p,
    float* __restrict__ out) {
  __shared__ float tile[2][kBufF];     // 64 KB double buffer -> 2 blocks/CU

  const int tid = threadIdx.x;
  const int lane = tid & 63;
  const int wave = tid >> 6;
  const int half = tid >> 7;           // 0: ch 0-63, 1: ch 64-127
  const int px = tid & 127;
  const int z = blockIdx.x & (kNZ - 1);
  const int b = blockIdx.x >> 8;       // kNZ == 256
  const int pix = (int)((size_t)b * kZX + z * kNX + px);

  const float fs = fs_p[0];
  const float c0 = c0_p[0];
  const float kk = fs / c0;
  const float base = fs * (d_tx[pix] / c0 + t0[b]);

  const float* rfb = rf + (size_t)b * kC * kNS;
  const float* drxp =
      d_rx + (size_t)half * kHalfC * kZX + (size_t)z * kNX + px;

  float F[16], win[16], head[16];
  float Sall = 0.0f;
#pragma unroll
  for (int i = 0; i < 16; ++i) F[i] = 0.0f;

  float drxA[kRows], drxB[kRows];

  // ---- phase A: 16 steps of 4 channels per half, double-buffered ----
  stage_step(rfb, tile[0], 0, wave, lane);
  load_drx4(drxp, 0, drxA);
  __syncthreads();

  STEP(0, 0, true, drxA, drxB);
  STEP(1, 4, true, drxB, drxA);
  STEP(2, 8, true, drxA, drxB);
  STEP(3, 12, true, drxB, drxA);
#pragma unroll 1
  for (int g = 1; g < 4; ++g) {
    const int q = g * 4;
    STEP(q + 0, 0, false, drxA, drxB);
    STEP(q + 1, 4, false, drxB, drxA);
    STEP(q + 2, 8, false, drxA, drxB);
    STEP(q + 3, 12, false, drxB, drxA);
  }
  // per half: head[i] = x_{h*64+i}, win[i] = x_{h*64+48+i},
  //           F[d] = sum_{j in half, j-d in half} x_j x_{j-d}

  // ---- exchange: lo exports its 49-float summary via the dead tile ----
  float* xch = tile[0];                // 49*128*4 B = 25 KB < 32 KB
  if (half == 0) {
#pragma unroll
    for (int i = 0; i < 16; ++i) xch[i * 128 + px] = F[i];
#pragma unroll
    for (int i = 0; i < 16; ++i) xch[(16 + i) * 128 + px] = win[i];
#pragma unroll
    for (int i = 0; i < 16; ++i) xch[(32 + i) * 128 + px] = head[i];
    xch[48 * 128 + px] = Sall;
  }
  __syncthreads();
  if (half == 0) return;               // hi waves solve

  float hlo[16];                       // global head = lo's head
  {
    float wlo[16];
#pragma unroll
    for (int i = 0; i < 16; ++i) wlo[i] = xch[(16 + i) * 128 + px];
#pragma unroll
    for (int i = 0; i < 16; ++i) hlo[i] = xch[(32 + i) * 128 + px];
    Sall += xch[48 * 128 + px];
    F[0] += xch[0 * 128 + px];
#pragma unroll
    for (int d = 1; d < 16; ++d) {
      float s = xch[d * 128 + px];     // F_lo[d]
#pragma unroll
      for (int i = 0; i < d; ++i) s = fmaf(head[i], wlo[16 - d + i], s);
      F[d] += s;                       // + cross terms head_hi x win_lo
    }
  }
  // now: hlo = x_{0..15}, win = x_{112..127}, F[d] = full lag sums

  // ---- assemble R (unscaled; packed upper triangle) ----
  float Ru[136];
#pragma unroll
  for (int d = 0; d < 16; ++d) {
    float t0s = 0.0f;                  // tail beyond window of l=0
#pragma unroll
    for (int i = d + 1; i < 16; ++i) t0s = fmaf(win[i - d], win[i], t0s);
    Ru[tri(0, d)] = F[d] - t0s;
#pragma unroll
    for (int l = 1; l < 16 - d; ++l)
      Ru[tri(l, l + d)] = Ru[tri(l - 1, l - 1 + d)] -
                          hlo[l - 1] * hlo[l - 1 + d] +
                          win[l] * win[l + d];
  }

  // diagonal loading: += DL * trace/16
  float tr = 0.0f;
#pragma unroll
  for (int l = 0; l < 16; ++l) tr += Ru[tri(l, l)];
  const float dl = tr * (0.05f / 16.0f);
#pragma unroll
  for (int l = 0; l < 16; ++l) Ru[tri(l, l)] += dl;

  // x (unscaled window sums): X[l] = sum_{j=l}^{l+112} xf[j]
  float X[16];
  {
    float s = Sall;
#pragma unroll
    for (int i = 1; i < 16; ++i) s -= win[i];
    X[0] = s;
#pragma unroll
    for (int l = 1; l < 16; ++l) X[l] = X[l - 1] - hlo[l - 1] + win[l];
  }

  // ---- Cholesky R = L L^T (rsqrt form), L[i][j] at Ru[tri(j,i)] ----
  float inv[16];
#pragma unroll
  for (int j = 0; j < 16; ++j) {
    float d = Ru[tri(j, j)];
#pragma unroll
    for (int p = 0; p < j; ++p) d = fmaf(-Ru[tri(p, j)], Ru[tri(p, j)], d);
    inv[j] = rsqrtf(d);
#pragma unroll
    for (int i = j + 1; i < 16; ++i) {
      float s = Ru[tri(j, i)];
#pragma unroll
      for (int p = 0; p < j; ++p) s = fmaf(-Ru[tri(p, i)], Ru[tri(p, j)], s);
      Ru[tri(j, i)] = s * inv[j];
    }
  }

  // forward solve L y = 1
  float yv[16];
#pragma unroll
  for (int i = 0; i < 16; ++i) {
    float s = 1.0f;
#pragma unroll
    for (int j = 0; j < i; ++j) s = fmaf(-Ru[tri(j, i)], yv[j], s);
    yv[i] = s * inv[i];
  }
  // back solve L^T u = y
  float u[16];
#pragma unroll
  for (int i = 15; i >= 0; --i) {
    float s = yv[i];
#pragma unroll
    for (int j = i + 1; j < 16; ++j) s = fmaf(-Ru[tri(i, j)], u[j], s);
    u[i] = s * inv[i];
  }

  float su = 0.0f, dot = 0.0f;
#pragma unroll
  for (int i = 0; i < 16; ++i) {
    su += u[i];
    dot = fmaf(u[i], X[i], dot);
  }
  // y = dot/(M*su + 1e-10)  (matches reference up to scale algebra)
  out[pix] = dot / (113.0f * su + 1e-10f);
}

}  // namespace

extern "C" void kernel_launch(void* const* d_in, const int* in_sizes, int n_in,
                              void* d_out, int out_size, void* d_ws,
                              size_t ws_size, hipStream_t stream) {
  const float* rf   = (const float*)d_in[0];
  const float* t0   = (const float*)d_in[1];
  const float* d_tx = (const float*)d_in[2];
  const float* d_rx = (const float*)d_in[3];
  const float* fs   = (const float*)d_in[4];
  // d_in[5] = f0 (unused), d_in[7] = apod (unused by reference)
  const float* c0   = (const float*)d_in[6];
  float* out = (float*)d_out;

  hipLaunchKernelGGL(mvb_fused_kernel, dim3(kB * kNZ), dim3(kTPB), 0, stream,
                     rf, t0, d_tx, d_rx, fs, c0, out);
}